// Round 7
// baseline (205.405 us; speedup 1.0000x reference)
//
#include <hip/hip_runtime.h>

#define B_DIM 1024
#define C_DIM 256
#define ELL   9
#define E_DIM 10
#define K1    1
#define K2    4
#define K3    20

#define N_CUBIC 165                 // monomials a<=b<=c
#define N_QUAD  45                  // pairs a<=b
// q-sliced table layout: per q: [165*20 cubic][45*4 quad][9 lin][3 pad]
#define Q_CUBIC 0
#define Q_QUAD  (N_CUBIC * K3)              // 3300
#define Q_LIN   (Q_QUAD + N_QUAD * K2)      // 3480
#define Q_SIZE  3492                        // padded to 16B multiple
#define TBL_FLOATS (4 * Q_SIZE)             // 13968
#define MONO3_OFF  TBL_FLOATS               // int region after floats
#define MONO2_OFF  (MONO3_OFF + N_CUBIC)
#define WS_TOTAL   (MONO2_OFF + N_QUAD)     // 14178 words

// ---------------------------------------------------------------------------
// Kernel A: build q-sliced symmetrized tables + packed monomial decode words.
// mono3[m] = pair_index(a,b) | (c2 << 8); mono2[p] = a | (b<<4).  (validated r6)
// ---------------------------------------------------------------------------
__global__ void build_tables(const float* __restrict__ U1_l0,
                             const float* __restrict__ U2_l0,
                             const float* __restrict__ U3_l0,
                             const float* __restrict__ U1_l1,
                             const float* __restrict__ U2_l1,
                             const float* __restrict__ U3_l1,
                             float* __restrict__ tbl)
{
    int idx = blockIdx.x * blockDim.x + threadIdx.x;
    if (idx >= WS_TOTAL) return;

    if (idx < TBL_FLOATS) {
        int q = idx / Q_SIZE;       // 0 = l0; 1..3 = l1 v=q-1
        int r = idx % Q_SIZE;
        int v = q - 1;
        float s = 0.f;
        if (r < Q_QUAD) {
            int m = r / K3, k = r % K3;
            int a = 0, b = 0, c = 0, cnt = 0;
            for (int ai = 0; ai < ELL; ++ai)
                for (int bi = ai; bi < ELL; ++bi)
                    for (int ci = bi; ci < ELL; ++ci) {
                        if (cnt == m) { a = ai; b = bi; c = ci; }
                        ++cnt;
                    }
            int P[6][3] = {{a,b,c},{a,c,b},{b,a,c},{b,c,a},{c,a,b},{c,b,a}};
            for (int t = 0; t < 6; ++t) {
                bool dup = false;
                for (int u = 0; u < t; ++u)
                    if (P[u][0]==P[t][0] && P[u][1]==P[t][1] && P[u][2]==P[t][2]) { dup = true; break; }
                if (dup) continue;
                int p0 = P[t][0], p1 = P[t][1], p2 = P[t][2];
                if (q == 0) s += U3_l0[((p0*ELL + p1)*ELL + p2)*K3 + k];
                else        s += U3_l1[(((v*ELL + p0)*ELL + p1)*ELL + p2)*K3 + k];
            }
        } else if (r < Q_LIN) {
            int rr = r - Q_QUAD;
            int p = rr / K2, k = rr % K2;
            int a = 0, b = 0, cnt = 0;
            for (int ai = 0; ai < ELL; ++ai)
                for (int bi = ai; bi < ELL; ++bi) {
                    if (cnt == p) { a = ai; b = bi; }
                    ++cnt;
                }
            for (int t = 0; t < 2; ++t) {
                if (t == 1 && a == b) break;
                int p0 = (t == 0) ? a : b;
                int p1 = (t == 0) ? b : a;
                if (q == 0) s += U2_l0[(p0*ELL + p1)*K2 + k];
                else        s += U2_l1[((v*ELL + p0)*ELL + p1)*K2 + k];
            }
        } else if (r < Q_LIN + ELL) {
            int i = r - Q_LIN;
            s = (q == 0) ? U1_l0[i] : U1_l1[v*ELL + i];
        } else {
            s = 0.f;   // pad
        }
        tbl[idx] = s;
    } else if (idx < MONO2_OFF) {
        int m = idx - MONO3_OFF;
        int a = 0, b = 0, c = 0, cnt = 0;
        for (int ai = 0; ai < ELL; ++ai)
            for (int bi = ai; bi < ELL; ++bi)
                for (int ci = bi; ci < ELL; ++ci) {
                    if (cnt == m) { a = ai; b = bi; c = ci; }
                    ++cnt;
                }
        // pair index of (a,b) in lex order over a<=b
        int p = 0, pc = 0;
        for (int ai = 0; ai < ELL; ++ai)
            for (int bi = ai; bi < ELL; ++bi) {
                if (ai == a && bi == b) p = pc;
                ++pc;
            }
        ((int*)tbl)[idx] = p | (c << 8);
    } else {
        int p = idx - MONO2_OFF;
        int a = 0, b = 0, cnt = 0;
        for (int ai = 0; ai < ELL; ++ai)
            for (int bi = ai; bi < ELL; ++bi) {
                if (cnt == p) { a = ai; b = bi; }
                ++cnt;
            }
        ((int*)tbl)[idx] = a | (b << 4);
    }
}

// ---------------------------------------------------------------------------
// Kernel B v7: 2048 blocks = (b, c-half), 256 threads. Wave = output group q
// (readfirstlane -> SGPR -> s_load table path). Each thread owns 2 contiguous
// c's: 50 static accumulators (fits 128-VGPR cap, no spill — r6's failure).
// P2[45][128] pair products staged in LDS; cubic iter = 2x ds_read_b64
// (stride-8B, conflict-free) + 2 mul + 40 FMA. VALU-bound by construction.
// ---------------------------------------------------------------------------
__global__ __launch_bounds__(256, 4) void symcon_main(
    const float* __restrict__ x,  const float* __restrict__ y,
    const float* __restrict__ w1_l0, const float* __restrict__ w2_l0, const float* __restrict__ w3_l0,
    const float* __restrict__ w1_l1, const float* __restrict__ w2_l1, const float* __restrict__ w3_l1,
    const float* __restrict__ tbl, const int* __restrict__ mono3,
    const int* __restrict__ mono2, float* __restrict__ out)
{
    const int bid  = blockIdx.x;
    const int b    = bid >> 1;
    const int half = bid & 1;
    const int tid  = threadIdx.x;
    const int q    = __builtin_amdgcn_readfirstlane(tid >> 6);  // 0..3, SGPR
    const int lane = tid & 63;
    const int ci   = lane << 1;                  // 0..126 within half
    const int c    = (half << 7) + ci;           // global channel of pair start

    __shared__ float xs[ELL][128];               //  4.6 KB
    __shared__ float P2[N_QUAD][128];            // 23.0 KB

    // ---- stage x (transposed) for this c-half ----
    for (int t = tid; t < ELL * 128; t += 256) {
        int i  = t >> 7;
        int cc = t & 127;
        xs[i][cc] = x[(size_t)(b*C_DIM + (half << 7) + cc)*ELL + i];
    }
    __syncthreads();
    // ---- stage pair products ----
    for (int t = tid; t < N_QUAD * 128; t += 256) {
        int p  = t >> 7;
        int cc = t & 127;
        int e2 = mono2[p];
        P2[p][cc] = xs[e2 & 15][cc] * xs[(e2 >> 4) & 15][cc];
    }
    __syncthreads();

    float acc3[2][K3];
    #pragma unroll
    for (int g = 0; g < 2; ++g)
        #pragma unroll
        for (int j = 0; j < K3; ++j) acc3[g][j] = 0.f;
    float acc2v[2][K2];
    #pragma unroll
    for (int g = 0; g < 2; ++g)
        #pragma unroll
        for (int j = 0; j < K2; ++j) acc2v[g][j] = 0.f;
    float acc1v[2] = {0.f, 0.f};

    const float* tq = tbl + q * Q_SIZE;          // wave-uniform -> s_load path

    // ---- cubic: 165 monomials ----
    #pragma unroll 2
    for (int m = 0; m < N_CUBIC; ++m) {
        int e3 = mono3[m];                       // uniform s_load
        float2 pp = *(const float2*)&P2[e3 & 255][ci];
        float2 xx = *(const float2*)&xs[e3 >> 8][ci];
        float x30 = pp.x * xx.x;
        float x31 = pp.y * xx.y;
        const float* r = tq + Q_CUBIC + m*K3;
        #pragma unroll
        for (int j = 0; j < K3; ++j) {
            float tv = r[j];                     // SGPR operand
            acc3[0][j] = fmaf(tv, x30, acc3[0][j]);
            acc3[1][j] = fmaf(tv, x31, acc3[1][j]);
        }
    }
    // ---- quadratic: 45 pairs (table rows in pair order, matches P2) ----
    #pragma unroll 2
    for (int p = 0; p < N_QUAD; ++p) {
        float2 pp = *(const float2*)&P2[p][ci];
        const float* r = tq + Q_QUAD + p*K2;
        #pragma unroll
        for (int j = 0; j < K2; ++j) {
            float tv = r[j];
            acc2v[0][j] = fmaf(tv, pp.x, acc2v[0][j]);
            acc2v[1][j] = fmaf(tv, pp.y, acc2v[1][j]);
        }
    }
    // ---- linear ----
    #pragma unroll
    for (int i = 0; i < ELL; ++i) {
        float2 xx = *(const float2*)&xs[i][ci];
        float tv = tq[Q_LIN + i];
        acc1v[0] = fmaf(tv, xx.x, acc1v[0]);
        acc1v[1] = fmaf(tv, xx.y, acc1v[1]);
    }

    // ---- combine: w~[k,c] on the fly (weights L2-hot; float2 loads) ----
    const float* w3 = (q == 0) ? w3_l0 : w3_l1;
    const float* w2 = (q == 0) ? w2_l0 : w2_l1;
    const float* w1 = (q == 0) ? w1_l0 : w1_l1;

    float yb[E_DIM];
    #pragma unroll
    for (int e = 0; e < E_DIM; ++e) yb[e] = y[b*E_DIM + e];  // uniform -> s_load

    float o0 = 0.f, o1 = 0.f;
    #pragma unroll 2
    for (int k = 0; k < K3; ++k) {
        float wt0 = 0.f, wt1 = 0.f;
        #pragma unroll
        for (int e = 0; e < E_DIM; ++e) {
            float2 wv = *(const float2*)&w3[(e*K3 + k)*C_DIM + c];
            wt0 = fmaf(yb[e], wv.x, wt0);
            wt1 = fmaf(yb[e], wv.y, wt1);
        }
        o0 = fmaf(wt0, acc3[0][k], o0);
        o1 = fmaf(wt1, acc3[1][k], o1);
    }
    #pragma unroll
    for (int k = 0; k < K2; ++k) {
        float wt0 = 0.f, wt1 = 0.f;
        #pragma unroll
        for (int e = 0; e < E_DIM; ++e) {
            float2 wv = *(const float2*)&w2[(e*K2 + k)*C_DIM + c];
            wt0 = fmaf(yb[e], wv.x, wt0);
            wt1 = fmaf(yb[e], wv.y, wt1);
        }
        o0 = fmaf(wt0, acc2v[0][k], o0);
        o1 = fmaf(wt1, acc2v[1][k], o1);
    }
    {
        float wt0 = 0.f, wt1 = 0.f;
        #pragma unroll
        for (int e = 0; e < E_DIM; ++e) {
            float2 wv = *(const float2*)&w1[e*C_DIM + c];
            wt0 = fmaf(yb[e], wv.x, wt0);
            wt1 = fmaf(yb[e], wv.y, wt1);
        }
        o0 = fmaf(wt0, acc1v[0], o0);
        o1 = fmaf(wt1, acc1v[1], o1);
    }

    if (q == 0) {
        *(float2*)&out[b*C_DIM + c] = make_float2(o0, o1);
    } else {
        size_t base = (size_t)B_DIM*C_DIM + (size_t)(b*C_DIM + c)*3 + (q - 1);
        out[base    ] = o0;
        out[base + 3] = o1;
    }
}

// ---------------------------------------------------------------------------
extern "C" void kernel_launch(void* const* d_in, const int* in_sizes, int n_in,
                              void* d_out, int out_size, void* d_ws, size_t ws_size,
                              hipStream_t stream)
{
    const float* x     = (const float*)d_in[0];
    const float* y     = (const float*)d_in[1];
    const float* U1_l0 = (const float*)d_in[2];
    const float* U2_l0 = (const float*)d_in[3];
    const float* U3_l0 = (const float*)d_in[4];
    const float* U1_l1 = (const float*)d_in[5];
    const float* U2_l1 = (const float*)d_in[6];
    const float* U3_l1 = (const float*)d_in[7];
    const float* w1_l0 = (const float*)d_in[8];
    const float* w2_l0 = (const float*)d_in[9];
    const float* w3_l0 = (const float*)d_in[10];
    const float* w1_l1 = (const float*)d_in[11];
    const float* w2_l1 = (const float*)d_in[12];
    const float* w3_l1 = (const float*)d_in[13];

    float* tbl = (float*)d_ws;               // 56.7 KB used
    const int* mono3 = (const int*)((float*)d_ws + MONO3_OFF);
    const int* mono2 = (const int*)((float*)d_ws + MONO2_OFF);
    float* outp = (float*)d_out;

    build_tables<<<(WS_TOTAL + 255)/256, 256, 0, stream>>>(
        U1_l0, U2_l0, U3_l0, U1_l1, U2_l1, U3_l1, tbl);

    symcon_main<<<2*B_DIM, 256, 0, stream>>>(
        x, y, w1_l0, w2_l0, w3_l0, w1_l1, w2_l1, w3_l1, tbl, mono3, mono2, outp);
}

// Round 8
// 114.080 us; speedup vs baseline: 1.8005x; 1.8005x over previous
//
#include <hip/hip_runtime.h>

#define B_DIM 1024
#define C_DIM 256
#define ELL   9
#define E_DIM 10
#define K1    1
#define K2    4
#define K3    20

// GEMM geometry: M = B*C rows, K = 224 (219 monomials + pad), N = 112 (4q x 28)
#define N_MONO3 165
#define N_MONO2 45
#define N_MONO  219
#define K_PAD   224
#define KT_N    7            // 224 / 32
#define NT_N    7            // 112 / 16
#define TP_ELEMS (KT_N * NT_N * 64 * 8)   // 25088 fp16, fragment-ordered B
#define MROW    232          // fp16 pitch of M in LDS (16B aligned, 2-way banks)
#define BROW    113          // f32 pitch of basis in LDS (2-way banks)

typedef _Float16 half8 __attribute__((ext_vector_type(8)));
typedef float    f32x4 __attribute__((ext_vector_type(4)));

// ---------------------------------------------------------------------------
// Symmetrized coefficient T[k][n]:  k = monomial row, n = q*28 + t,
// t<20: cubic channel k3=t; 20<=t<24: quad channel k2=t-20; t==24: linear.
// ---------------------------------------------------------------------------
__device__ float table_val(int k, int n,
    const float* U1_l0, const float* U2_l0, const float* U3_l0,
    const float* U1_l1, const float* U2_l1, const float* U3_l1)
{
    int q = n / 28, t = n % 28;
    if (t >= 25 || k >= N_MONO) return 0.f;
    if (k < N_MONO3) {
        if (t >= K3) return 0.f;
        int a=0,b=0,c=0,cnt=0;
        for (int ai=0; ai<ELL; ++ai)
            for (int bi=ai; bi<ELL; ++bi)
                for (int ci=bi; ci<ELL; ++ci) { if (cnt==k){a=ai;b=bi;c=ci;} ++cnt; }
        int P[6][3] = {{a,b,c},{a,c,b},{b,a,c},{b,c,a},{c,a,b},{c,b,a}};
        float s = 0.f;
        for (int tt=0; tt<6; ++tt) {
            bool dup=false;
            for (int u=0; u<tt; ++u)
                if (P[u][0]==P[tt][0]&&P[u][1]==P[tt][1]&&P[u][2]==P[tt][2]) {dup=true;break;}
            if (dup) continue;
            int p0=P[tt][0], p1=P[tt][1], p2=P[tt][2];
            s += (q==0) ? U3_l0[((p0*ELL+p1)*ELL+p2)*K3 + t]
                        : U3_l1[((((q-1)*ELL+p0)*ELL+p1)*ELL+p2)*K3 + t];
        }
        return s;
    } else if (k < N_MONO3 + N_MONO2) {
        if (t < K3 || t >= K3 + K2) return 0.f;
        int pidx = k - N_MONO3, kk = t - K3;
        int a=0,b=0,cnt=0;
        for (int ai=0; ai<ELL; ++ai)
            for (int bi=ai; bi<ELL; ++bi) { if (cnt==pidx){a=ai;b=bi;} ++cnt; }
        float s = 0.f;
        for (int tt=0; tt<2; ++tt) {
            if (tt==1 && a==b) break;
            int p0 = tt ? b : a, p1 = tt ? a : b;
            s += (q==0) ? U2_l0[(p0*ELL+p1)*K2 + kk]
                        : U2_l1[(((q-1)*ELL+p0)*ELL+p1)*K2 + kk];
        }
        return s;
    } else {
        if (t != K3 + K2) return 0.f;
        int i = k - (N_MONO3 + N_MONO2);
        return (q==0) ? U1_l0[i] : U1_l1[(q-1)*ELL + i];
    }
}

// ---------------------------------------------------------------------------
// Kernel A: pack T into MFMA B-fragment order (fp16) + monomial codes.
// B-fragment layout for mfma_f32_16x16x32_f16: lane ln holds 8 fp16 with
// n = nt*16 + (ln&15), k = kt*32 + (ln>>4)*8 + elem.
// mono[m]: three 4-bit indices into xs row (9..15 read as 1.0f).
// ---------------------------------------------------------------------------
__global__ void build_tables(const float* __restrict__ U1_l0,
                             const float* __restrict__ U2_l0,
                             const float* __restrict__ U3_l0,
                             const float* __restrict__ U1_l1,
                             const float* __restrict__ U2_l1,
                             const float* __restrict__ U3_l1,
                             _Float16* __restrict__ Tp,
                             int* __restrict__ mono)
{
    int idx = blockIdx.x * blockDim.x + threadIdx.x;
    if (idx < TP_ELEMS) {
        int e    = idx & 7;
        int lane = (idx >> 3) & 63;
        int tile = idx >> 9;            // 0..48
        int nt   = tile % NT_N;
        int kt   = tile / NT_N;
        int k = kt*32 + (lane >> 4)*8 + e;
        int n = nt*16 + (lane & 15);
        Tp[idx] = (_Float16)table_val(k, n, U1_l0, U2_l0, U3_l0, U1_l1, U2_l1, U3_l1);
    } else if (idx < TP_ELEMS + N_MONO) {
        int m = idx - TP_ELEMS;
        int code;
        if (m < N_MONO3) {
            int a=0,b=0,c=0,cnt=0;
            for (int ai=0; ai<ELL; ++ai)
                for (int bi=ai; bi<ELL; ++bi)
                    for (int ci=bi; ci<ELL; ++ci) { if (cnt==m){a=ai;b=bi;c=ci;} ++cnt; }
            code = a | (b<<4) | (c<<8);
        } else if (m < N_MONO3 + N_MONO2) {
            int p = m - N_MONO3;
            int a=0,b=0,cnt=0;
            for (int ai=0; ai<ELL; ++ai)
                for (int bi=ai; bi<ELL; ++bi) { if (cnt==p){a=ai;b=bi;} ++cnt; }
            code = a | (b<<4) | (9<<8);
        } else {
            int i = m - (N_MONO3 + N_MONO2);
            code = i | (9<<4) | (9<<8);
        }
        mono[m] = code;
    }
}

// ---------------------------------------------------------------------------
// Kernel B: 4096 blocks x 256 threads; block = 64 consecutive (b,c) rows
// (single b per block since 64 | 256). Phases:
//   1. stage x -> xs[64][17] (cols 9..16 = 1.0 so quad/linear monomials use
//      the same 3-factor product path)
//   2. M[64][224] fp16 in LDS (pitch 232)
//   3. MFMA GEMM: wave w owns rows w*16..w*16+15; 7 k-steps x 7 n-tiles,
//      B-fragments straight from global (L2-hot, 50 KB)
//   4. basis f32 back to LDS (reuse M region, pitch 113)
//   5. vector epilogue: wave = q, lane = c-row; w~ on the fly
// ---------------------------------------------------------------------------
__global__ __launch_bounds__(256) void symcon_mfma(
    const float* __restrict__ x,  const float* __restrict__ y,
    const float* __restrict__ w1_l0, const float* __restrict__ w2_l0, const float* __restrict__ w3_l0,
    const float* __restrict__ w1_l1, const float* __restrict__ w2_l1, const float* __restrict__ w3_l1,
    const _Float16* __restrict__ Tp, const int* __restrict__ mono,
    float* __restrict__ out)
{
    const int bc0 = blockIdx.x * 64;
    const int b   = bc0 >> 8;
    const int cb  = bc0 & 255;
    const int tid = threadIdx.x;
    const int w   = __builtin_amdgcn_readfirstlane(tid >> 6);  // wave id, SGPR
    const int ln  = tid & 63;

    __shared__ __align__(16) _Float16 Mh[64 * MROW];   // 29696 B (reused as basis)
    __shared__ float xs[64][17];                       //  4352 B

    // ---- 1. stage x ----
    for (int v = tid; v < 64*17; v += 256) {
        int p = v / 17, i = v % 17;
        xs[p][i] = (i < ELL) ? x[(size_t)(bc0 + p)*ELL + i] : 1.0f;
    }
    __syncthreads();

    // ---- 2. build M (two fp16 monomials per 32-bit LDS write) ----
    {
        unsigned int* Mw = (unsigned int*)Mh;
        for (int v = tid; v < (K_PAD/2)*64; v += 256) {
            int m2 = v >> 6, p = v & 63;       // m2 wave-uniform -> s_load codes
            int m0 = 2*m2, m1 = m0 + 1;
            float pr0 = 0.f, pr1 = 0.f;
            if (m0 < N_MONO) { int cd = mono[m0];
                pr0 = xs[p][cd & 15] * xs[p][(cd>>4) & 15] * xs[p][(cd>>8) & 15]; }
            if (m1 < N_MONO) { int cd = mono[m1];
                pr1 = xs[p][cd & 15] * xs[p][(cd>>4) & 15] * xs[p][(cd>>8) & 15]; }
            union { _Float16 h[2]; unsigned int u; } cv;
            cv.h[0] = (_Float16)pr0; cv.h[1] = (_Float16)pr1;
            Mw[p*(MROW/2) + m2] = cv.u;
        }
    }
    __syncthreads();

    // ---- 3. MFMA GEMM ----
    f32x4 acc[NT_N];
    #pragma unroll
    for (int nt = 0; nt < NT_N; ++nt) acc[nt] = (f32x4){0.f, 0.f, 0.f, 0.f};
    {
        const int row  = w*16 + (ln & 15);
        const int kgrp = (ln >> 4) * 8;
        const half8* Bp = (const half8*)Tp;
        #pragma unroll
        for (int kt = 0; kt < KT_N; ++kt) {
            half8 a = *(const half8*)&Mh[row*MROW + kt*32 + kgrp];
            #pragma unroll
            for (int nt = 0; nt < NT_N; ++nt) {
                half8 bf = Bp[(kt*NT_N + nt)*64 + ln];
                acc[nt] = __builtin_amdgcn_mfma_f32_16x16x32_f16(a, bf, acc[nt], 0, 0, 0);
            }
        }
    }
    __syncthreads();   // all waves done reading Mh

    // ---- 4. basis -> LDS (D layout: col = ln&15, row = (ln>>4)*4 + reg) ----
    {
        float* basis = (float*)Mh;
        const int colg = ln & 15;
        const int rowg = (ln >> 4) * 4;
        #pragma unroll
        for (int nt = 0; nt < NT_N; ++nt)
            #pragma unroll
            for (int j = 0; j < 4; ++j)
                basis[(w*16 + rowg + j)*BROW + nt*16 + colg] = acc[nt][j];
    }
    __syncthreads();

    // ---- 5. epilogue ----
    {
        const float* basis = (const float*)Mh;
        const int q = w;
        const int p = ln;
        const int c = cb + p;
        const float* w3 = (q == 0) ? w3_l0 : w3_l1;
        const float* w2 = (q == 0) ? w2_l0 : w2_l1;
        const float* w1 = (q == 0) ? w1_l0 : w1_l1;
        float yb[E_DIM];
        #pragma unroll
        for (int e = 0; e < E_DIM; ++e) yb[e] = y[b*E_DIM + e];

        const float* brow = basis + p*BROW + q*28;
        float o = 0.f;
        #pragma unroll 4
        for (int k = 0; k < K3; ++k) {
            float wt = 0.f;
            #pragma unroll
            for (int e = 0; e < E_DIM; ++e)
                wt = fmaf(yb[e], w3[(e*K3 + k)*C_DIM + c], wt);
            o = fmaf(wt, brow[k], o);
        }
        #pragma unroll
        for (int k = 0; k < K2; ++k) {
            float wt = 0.f;
            #pragma unroll
            for (int e = 0; e < E_DIM; ++e)
                wt = fmaf(yb[e], w2[(e*K2 + k)*C_DIM + c], wt);
            o = fmaf(wt, brow[K3 + k], o);
        }
        {
            float wt = 0.f;
            #pragma unroll
            for (int e = 0; e < E_DIM; ++e)
                wt = fmaf(yb[e], w1[e*C_DIM + c], wt);
            o = fmaf(wt, brow[K3 + K2], o);
        }

        if (q == 0) out[b*C_DIM + c] = o;
        else        out[B_DIM*C_DIM + (size_t)(b*C_DIM + c)*3 + (q - 1)] = o;
    }
}

// ---------------------------------------------------------------------------
extern "C" void kernel_launch(void* const* d_in, const int* in_sizes, int n_in,
                              void* d_out, int out_size, void* d_ws, size_t ws_size,
                              hipStream_t stream)
{
    const float* x     = (const float*)d_in[0];
    const float* y     = (const float*)d_in[1];
    const float* U1_l0 = (const float*)d_in[2];
    const float* U2_l0 = (const float*)d_in[3];
    const float* U3_l0 = (const float*)d_in[4];
    const float* U1_l1 = (const float*)d_in[5];
    const float* U2_l1 = (const float*)d_in[6];
    const float* U3_l1 = (const float*)d_in[7];
    const float* w1_l0 = (const float*)d_in[8];
    const float* w2_l0 = (const float*)d_in[9];
    const float* w3_l0 = (const float*)d_in[10];
    const float* w1_l1 = (const float*)d_in[11];
    const float* w2_l1 = (const float*)d_in[12];
    const float* w3_l1 = (const float*)d_in[13];

    _Float16* Tp  = (_Float16*)d_ws;                       // 50176 B
    int*      mon = (int*)((char*)d_ws + TP_ELEMS * 2);    // 876 B
    float*    outp = (float*)d_out;

    build_tables<<<(TP_ELEMS + N_MONO + 255)/256, 256, 0, stream>>>(
        U1_l0, U2_l0, U3_l0, U1_l1, U2_l1, U3_l1, Tp, mon);

    symcon_mfma<<<(B_DIM*C_DIM)/64, 256, 0, stream>>>(
        x, y, w1_l0, w2_l0, w3_l0, w1_l1, w2_l1, w3_l1, Tp, mon, outp);
}

// Round 9
// 45.000 us; speedup vs baseline: 4.5645x; 2.5351x over previous
//
#include <hip/hip_runtime.h>

#define B_DIM 1024
#define C_DIM 256
#define ELL   9
#define E_DIM 10
#define K1    1
#define K2    4
#define K3    20

// GEMM geometry: M = B*C rows, K = 224 (219 monomials + pad), N = 112 (4q x 28)
#define N_MONO3 165
#define N_MONO2 45
#define N_MONO  219
#define K_PAD   224
#define KT_N    7            // 224 / 32
#define NT_N    7            // 112 / 16
#define TP_ELEMS (KT_N * NT_N * 64 * 8)   // 25088 fp16, fragment-ordered B
#define MPITCH  232          // fp16 pitch of M rows in LDS (16B mult; 29x16B -> 2-way A-reads)
#define BPITCH  113          // f32 pitch of basis rows (odd words -> 2-way epilogue reads)
#define WT_CH   50           // 25 l1 channels + 25 l0 channels

typedef _Float16 half8 __attribute__((ext_vector_type(8)));
typedef float    f32x4 __attribute__((ext_vector_type(4)));

// ---------------------------------------------------------------------------
// Symmetrized coefficient T[k][n]:  k = monomial row (cubic lex 0..164, quad
// lex 165..209, linear 210..218, pad), n = q*28 + t (t<20 cubic ch, 20..23
// quad ch, 24 linear, 25..27 pad).   (validated r8)
// ---------------------------------------------------------------------------
__device__ float table_val(int k, int n,
    const float* U1_l0, const float* U2_l0, const float* U3_l0,
    const float* U1_l1, const float* U2_l1, const float* U3_l1)
{
    int q = n / 28, t = n % 28;
    if (t >= 25 || k >= N_MONO) return 0.f;
    if (k < N_MONO3) {
        if (t >= K3) return 0.f;
        int a=0,b=0,c=0,cnt=0;
        for (int ai=0; ai<ELL; ++ai)
            for (int bi=ai; bi<ELL; ++bi)
                for (int ci=bi; ci<ELL; ++ci) { if (cnt==k){a=ai;b=bi;c=ci;} ++cnt; }
        int P[6][3] = {{a,b,c},{a,c,b},{b,a,c},{b,c,a},{c,a,b},{c,b,a}};
        float s = 0.f;
        for (int tt=0; tt<6; ++tt) {
            bool dup=false;
            for (int u=0; u<tt; ++u)
                if (P[u][0]==P[tt][0]&&P[u][1]==P[tt][1]&&P[u][2]==P[tt][2]) {dup=true;break;}
            if (dup) continue;
            int p0=P[tt][0], p1=P[tt][1], p2=P[tt][2];
            s += (q==0) ? U3_l0[((p0*ELL+p1)*ELL+p2)*K3 + t]
                        : U3_l1[((((q-1)*ELL+p0)*ELL+p1)*ELL+p2)*K3 + t];
        }
        return s;
    } else if (k < N_MONO3 + N_MONO2) {
        if (t < K3 || t >= K3 + K2) return 0.f;
        int pidx = k - N_MONO3, kk = t - K3;
        int a=0,b=0,cnt=0;
        for (int ai=0; ai<ELL; ++ai)
            for (int bi=ai; bi<ELL; ++bi) { if (cnt==pidx){a=ai;b=bi;} ++cnt; }
        float s = 0.f;
        for (int tt=0; tt<2; ++tt) {
            if (tt==1 && a==b) break;
            int p0 = tt ? b : a, p1 = tt ? a : b;
            s += (q==0) ? U2_l0[(p0*ELL+p1)*K2 + kk]
                        : U2_l1[(((q-1)*ELL+p0)*ELL+p1)*K2 + kk];
        }
        return s;
    } else {
        if (t != K3 + K2) return 0.f;
        int i = k - (N_MONO3 + N_MONO2);
        return (q==0) ? U1_l0[i] : U1_l1[(q-1)*ELL + i];
    }
}

// ---------------------------------------------------------------------------
// Kernel A: pack T into MFMA B-fragment order (fp16).
// B-fragment for mfma_f32_16x16x32_f16: lane holds 8 fp16 with
// n = nt*16 + (lane&15), k = kt*32 + (lane>>4)*8 + elem.   (validated r8)
// ---------------------------------------------------------------------------
__global__ void build_tables(const float* __restrict__ U1_l0,
                             const float* __restrict__ U2_l0,
                             const float* __restrict__ U3_l0,
                             const float* __restrict__ U1_l1,
                             const float* __restrict__ U2_l1,
                             const float* __restrict__ U3_l1,
                             _Float16* __restrict__ Tp)
{
    int idx = blockIdx.x * blockDim.x + threadIdx.x;
    if (idx >= TP_ELEMS) return;
    int e    = idx & 7;
    int lane = (idx >> 3) & 63;
    int tile = idx >> 9;            // 0..48
    int nt   = tile % NT_N;
    int kt   = tile / NT_N;
    int k = kt*32 + (lane >> 4)*8 + e;
    int n = nt*16 + (lane & 15);
    Tp[idx] = (_Float16)table_val(k, n, U1_l0, U2_l0, U3_l0, U1_l1, U2_l1, U3_l1);
}

// ---------------------------------------------------------------------------
// Register-resident monomial emitter: all indices compile-time after unroll.
// Emits m in [CH*56, CH*56+56) into this row's M, packed 4 fp16 / ds_write_b64.
// Order MUST match table_val's k: cubic lex, quad lex, linear, pad.
// ---------------------------------------------------------------------------
template<int CH>
__device__ __forceinline__ void build_M_chunk(const float* xv, _Float16* Mrow)
{
    constexpr int LO = CH*56, HI = LO + 56;
    union { _Float16 h[4]; uint2 u2; } pk;
    int m = 0;
#define EMIT(val)                                                       \
    do { if (m >= LO && m < HI) {                                       \
            pk.h[m & 3] = (_Float16)(val);                              \
            if ((m & 3) == 3) *(uint2*)&Mrow[m - 3] = pk.u2;            \
         } ++m; } while (0)

    #pragma unroll
    for (int a = 0; a < ELL; ++a)
        #pragma unroll
        for (int b = a; b < ELL; ++b) {
            float xab = xv[a] * xv[b];
            #pragma unroll
            for (int c = b; c < ELL; ++c) EMIT(xab * xv[c]);
        }
    #pragma unroll
    for (int a = 0; a < ELL; ++a)
        #pragma unroll
        for (int b = a; b < ELL; ++b) EMIT(xv[a] * xv[b]);
    #pragma unroll
    for (int i = 0; i < ELL; ++i) EMIT(xv[i]);
    #pragma unroll
    for (int p = 0; p < K_PAD - N_MONO; ++p) EMIT(0.f);
#undef EMIT
}

// ---------------------------------------------------------------------------
// Kernel B: 4096 blocks x 256 threads; block = 64 consecutive (b,c) rows.
//   P1 : thread = row ln, wave = monomial chunk; x in registers, M built with
//        zero LDS reads (compile-time unroll), 14 ds_write_b64 / thread.
//   P1b: w~ staged once as fp16 [50][64] (coop float4 loads; kills 3x q-redundancy).
//   P3 : GEMM; wave owns 2 n-tiles x 4 row-tiles (B-traffic 200KB->50KB/block).
//   P4 : basis f32 -> LDS (reuse M region).
//   P5 : epilogue: wave = q, lane = row; dot(basis_row, wt_col), 25 FMA.
// ---------------------------------------------------------------------------
__global__ __launch_bounds__(256) void symcon_mfma(
    const float* __restrict__ x,  const float* __restrict__ y,
    const float* __restrict__ w1_l0, const float* __restrict__ w2_l0, const float* __restrict__ w3_l0,
    const float* __restrict__ w1_l1, const float* __restrict__ w2_l1, const float* __restrict__ w3_l1,
    const _Float16* __restrict__ Tp, float* __restrict__ out)
{
    const int bc0 = blockIdx.x * 64;
    const int b   = bc0 >> 8;
    const int cb  = bc0 & 255;
    const int tid = threadIdx.x;
    const int w   = __builtin_amdgcn_readfirstlane(tid >> 6);  // wave id, SGPR
    const int ln  = tid & 63;

    __shared__ __align__(16) _Float16 Mh[64 * MPITCH];   // 29696 B, reused as basis [64][113] f32
    __shared__ __align__(16) _Float16 wt[WT_CH][64];     //  6400 B

    // ---- P1: x -> registers; build this wave's monomial chunk ----
    {
        float xv[ELL];
        #pragma unroll
        for (int i = 0; i < ELL; ++i) xv[i] = x[(size_t)(bc0 + ln)*ELL + i];
        _Float16* Mrow = &Mh[ln * MPITCH];
        switch (w) {
            case 0:  build_M_chunk<0>(xv, Mrow); break;
            case 1:  build_M_chunk<1>(xv, Mrow); break;
            case 2:  build_M_chunk<2>(xv, Mrow); break;
            default: build_M_chunk<3>(xv, Mrow); break;
        }
    }

    // ---- P1b: stage w~ as fp16 (rows 0..24 = l1 ch t, rows 25..49 = l0) ----
    {
        float yb[E_DIM];
        #pragma unroll
        for (int e = 0; e < E_DIM; ++e) yb[e] = y[b*E_DIM + e];   // uniform -> s_load
        for (int v = tid; v < WT_CH * 16; v += 256) {
            int kk = v >> 4;                 // 0..49
            int c4 = (v & 15) << 2;          // 0,4,..,60
            int t  = (kk >= 25) ? kk - 25 : kk;
            const float* wp;
            int ke;
            if (t < K3)            { wp = (kk >= 25 ? w3_l0 : w3_l1) + (size_t)t*C_DIM;        ke = K3; }
            else if (t < K3 + K2)  { wp = (kk >= 25 ? w2_l0 : w2_l1) + (size_t)(t - K3)*C_DIM; ke = K2; }
            else                   { wp = (kk >= 25 ? w1_l0 : w1_l1);                          ke = K1; }
            float s0 = 0.f, s1 = 0.f, s2 = 0.f, s3 = 0.f;
            #pragma unroll
            for (int e = 0; e < E_DIM; ++e) {
                float4 wv = *(const float4*)&wp[(size_t)e*ke*C_DIM + cb + c4];
                s0 = fmaf(yb[e], wv.x, s0);
                s1 = fmaf(yb[e], wv.y, s1);
                s2 = fmaf(yb[e], wv.z, s2);
                s3 = fmaf(yb[e], wv.w, s3);
            }
            union { _Float16 h[4]; uint2 u2; } cv;
            cv.h[0] = (_Float16)s0; cv.h[1] = (_Float16)s1;
            cv.h[2] = (_Float16)s2; cv.h[3] = (_Float16)s3;
            *(uint2*)&wt[kk][c4] = cv.u2;
        }
    }
    __syncthreads();

    // ---- P3: GEMM, wave owns n-tiles {2w, 2w+1} x all 4 row-tiles ----
    f32x4 acc[2][4];
    #pragma unroll
    for (int u = 0; u < 2; ++u)
        #pragma unroll
        for (int rt = 0; rt < 4; ++rt) acc[u][rt] = (f32x4){0.f, 0.f, 0.f, 0.f};
    {
        const int l15 = ln & 15, lq = ln >> 4;
        const int ntb = 2 * w;
        const half8* Bp = (const half8*)Tp;
        #pragma unroll
        for (int kt = 0; kt < KT_N; ++kt) {
            half8 ar[4];
            #pragma unroll
            for (int rt = 0; rt < 4; ++rt)
                ar[rt] = *(const half8*)&Mh[(rt*16 + l15)*MPITCH + kt*32 + lq*8];
            #pragma unroll
            for (int u = 0; u < 2; ++u) {
                int nt = ntb + u;
                if (nt < NT_N) {
                    half8 bf = Bp[(kt*NT_N + nt)*64 + ln];
                    #pragma unroll
                    for (int rt = 0; rt < 4; ++rt)
                        acc[u][rt] = __builtin_amdgcn_mfma_f32_16x16x32_f16(ar[rt], bf, acc[u][rt], 0, 0, 0);
                }
            }
        }
    }
    __syncthreads();   // all waves done reading Mh

    // ---- P4: basis -> LDS (D layout: col = ln&15, row = (ln>>4)*4 + j) ----
    {
        float* basis = (float*)Mh;
        const int l15 = ln & 15, lq = ln >> 4;
        const int ntb = 2 * w;
        #pragma unroll
        for (int u = 0; u < 2; ++u) {
            int nt = ntb + u;
            if (nt < NT_N) {
                #pragma unroll
                for (int rt = 0; rt < 4; ++rt)
                    #pragma unroll
                    for (int j = 0; j < 4; ++j)
                        basis[(rt*16 + lq*4 + j)*BPITCH + nt*16 + l15] = acc[u][rt][j];
            }
        }
    }
    __syncthreads();

    // ---- P5: epilogue — wave = q, lane = row ----
    {
        const float* basis = (const float*)Mh;
        const float* brow  = basis + ln*BPITCH + w*28;
        const int    base  = (w == 0) ? 25 : 0;       // l0 rows live at 25..49
        float o = 0.f;
        #pragma unroll
        for (int k = 0; k < K3 + K2 + K1; ++k)
            o = fmaf((float)wt[base + k][ln], brow[k], o);

        const int c = cb + ln;
        if (w == 0) out[b*C_DIM + c] = o;
        else        out[B_DIM*C_DIM + (size_t)(b*C_DIM + c)*3 + (w - 1)] = o;
    }
}

// ---------------------------------------------------------------------------
extern "C" void kernel_launch(void* const* d_in, const int* in_sizes, int n_in,
                              void* d_out, int out_size, void* d_ws, size_t ws_size,
                              hipStream_t stream)
{
    const float* x     = (const float*)d_in[0];
    const float* y     = (const float*)d_in[1];
    const float* U1_l0 = (const float*)d_in[2];
    const float* U2_l0 = (const float*)d_in[3];
    const float* U3_l0 = (const float*)d_in[4];
    const float* U1_l1 = (const float*)d_in[5];
    const float* U2_l1 = (const float*)d_in[6];
    const float* U3_l1 = (const float*)d_in[7];
    const float* w1_l0 = (const float*)d_in[8];
    const float* w2_l0 = (const float*)d_in[9];
    const float* w3_l0 = (const float*)d_in[10];
    const float* w1_l1 = (const float*)d_in[11];
    const float* w2_l1 = (const float*)d_in[12];
    const float* w3_l1 = (const float*)d_in[13];

    _Float16* Tp   = (_Float16*)d_ws;     // 50176 B used
    float*    outp = (float*)d_out;

    build_tables<<<(TP_ELEMS + 255)/256, 256, 0, stream>>>(
        U1_l0, U2_l0, U3_l0, U1_l1, U2_l1, U3_l1, Tp);

    symcon_mfma<<<(B_DIM*C_DIM)/64, 256, 0, stream>>>(
        x, y, w1_l0, w2_l0, w3_l0, w1_l1, w2_l1, w3_l1, Tp, outp);
}

// Round 10
// 44.808 us; speedup vs baseline: 4.5841x; 1.0043x over previous
//
#include <hip/hip_runtime.h>

#define B_DIM 1024
#define C_DIM 256
#define ELL   9
#define E_DIM 10
#define K1    1
#define K2    4
#define K3    20

// GEMM geometry: M = B*C rows, K = 224 (219 monomials + pad), N = 112 (4q x 28)
#define N_MONO3 165
#define N_MONO2 45
#define N_MONO  219
#define K_PAD   224
#define KT_N    7            // 224 / 32
#define NT_N    7            // 112 / 16
#define TP_ELEMS (KT_N * NT_N * 64 * 8)   // 25088 fp16, fragment-ordered B
#define MPITCH  232          // fp16 pitch of M rows in LDS
#define BPITCH  113          // f32 pitch of basis rows
#define WT_CH   50           // 25 l1 channels + 25 l0 channels
#define BG      4            // b's per block

typedef _Float16 half8 __attribute__((ext_vector_type(8)));
typedef float    f32x4 __attribute__((ext_vector_type(4)));

// ---------------------------------------------------------------------------
// Symmetrized coefficient T[k][n] (validated r8/r9).
// ---------------------------------------------------------------------------
__device__ float table_val(int k, int n,
    const float* U1_l0, const float* U2_l0, const float* U3_l0,
    const float* U1_l1, const float* U2_l1, const float* U3_l1)
{
    int q = n / 28, t = n % 28;
    if (t >= 25 || k >= N_MONO) return 0.f;
    if (k < N_MONO3) {
        if (t >= K3) return 0.f;
        int a=0,b=0,c=0,cnt=0;
        for (int ai=0; ai<ELL; ++ai)
            for (int bi=ai; bi<ELL; ++bi)
                for (int ci=bi; ci<ELL; ++ci) { if (cnt==k){a=ai;b=bi;c=ci;} ++cnt; }
        int P[6][3] = {{a,b,c},{a,c,b},{b,a,c},{b,c,a},{c,a,b},{c,b,a}};
        float s = 0.f;
        for (int tt=0; tt<6; ++tt) {
            bool dup=false;
            for (int u=0; u<tt; ++u)
                if (P[u][0]==P[tt][0]&&P[u][1]==P[tt][1]&&P[u][2]==P[tt][2]) {dup=true;break;}
            if (dup) continue;
            int p0=P[tt][0], p1=P[tt][1], p2=P[tt][2];
            s += (q==0) ? U3_l0[((p0*ELL+p1)*ELL+p2)*K3 + t]
                        : U3_l1[((((q-1)*ELL+p0)*ELL+p1)*ELL+p2)*K3 + t];
        }
        return s;
    } else if (k < N_MONO3 + N_MONO2) {
        if (t < K3 || t >= K3 + K2) return 0.f;
        int pidx = k - N_MONO3, kk = t - K3;
        int a=0,b=0,cnt=0;
        for (int ai=0; ai<ELL; ++ai)
            for (int bi=ai; bi<ELL; ++bi) { if (cnt==pidx){a=ai;b=bi;} ++cnt; }
        float s = 0.f;
        for (int tt=0; tt<2; ++tt) {
            if (tt==1 && a==b) break;
            int p0 = tt ? b : a, p1 = tt ? a : b;
            s += (q==0) ? U2_l0[(p0*ELL+p1)*K2 + kk]
                        : U2_l1[(((q-1)*ELL+p0)*ELL+p1)*K2 + kk];
        }
        return s;
    } else {
        if (t != K3 + K2) return 0.f;
        int i = k - (N_MONO3 + N_MONO2);
        return (q==0) ? U1_l0[i] : U1_l1[(q-1)*ELL + i];
    }
}

// ---------------------------------------------------------------------------
// Kernel A: pack T into MFMA B-fragment order (fp16).  (validated r8/r9)
// ---------------------------------------------------------------------------
__global__ void build_tables(const float* __restrict__ U1_l0,
                             const float* __restrict__ U2_l0,
                             const float* __restrict__ U3_l0,
                             const float* __restrict__ U1_l1,
                             const float* __restrict__ U2_l1,
                             const float* __restrict__ U3_l1,
                             _Float16* __restrict__ Tp)
{
    int idx = blockIdx.x * blockDim.x + threadIdx.x;
    if (idx >= TP_ELEMS) return;
    int e    = idx & 7;
    int lane = (idx >> 3) & 63;
    int tile = idx >> 9;            // 0..48
    int nt   = tile % NT_N;
    int kt   = tile / NT_N;
    int k = kt*32 + (lane >> 4)*8 + e;
    int n = nt*16 + (lane & 15);
    Tp[idx] = (_Float16)table_val(k, n, U1_l0, U2_l0, U3_l0, U1_l1, U2_l1, U3_l1);
}

// ---------------------------------------------------------------------------
// Register-resident monomial emitter (validated r9). Compile-time indices.
// ---------------------------------------------------------------------------
template<int CH>
__device__ __forceinline__ void build_M_chunk(const float* xv, _Float16* Mrow)
{
    constexpr int LO = CH*56, HI = LO + 56;
    union { _Float16 h[4]; uint2 u2; } pk;
    int m = 0;
#define EMIT(val)                                                       \
    do { if (m >= LO && m < HI) {                                       \
            pk.h[m & 3] = (_Float16)(val);                              \
            if ((m & 3) == 3) *(uint2*)&Mrow[m - 3] = pk.u2;            \
         } ++m; } while (0)

    #pragma unroll
    for (int a = 0; a < ELL; ++a)
        #pragma unroll
        for (int b = a; b < ELL; ++b) {
            float xab = xv[a] * xv[b];
            #pragma unroll
            for (int c = b; c < ELL; ++c) EMIT(xab * xv[c]);
        }
    #pragma unroll
    for (int a = 0; a < ELL; ++a)
        #pragma unroll
        for (int b = a; b < ELL; ++b) EMIT(xv[a] * xv[b]);
    #pragma unroll
    for (int i = 0; i < ELL; ++i) EMIT(xv[i]);
    #pragma unroll
    for (int p = 0; p < K_PAD - N_MONO; ++p) EMIT(0.f);
#undef EMIT
}

// ---------------------------------------------------------------------------
// Kernel B: 1024 blocks = (b-group of 4, c-quarter of 64), 256 threads.
//   PW : w~ for all 4 b's staged at once — each weight float4 loaded ONCE,
//        FMA'd into 4 b-accumulators (kills the 4x cross-block redundancy).
//   Bld: B-fragments hoisted into registers, held across the 4 b-iterations.
//   per ib: P1 build M (reg, zero LDS reads) | P3 GEMM | P4 basis->LDS |
//           P5 epilogue with wt4[ib].
// ---------------------------------------------------------------------------
__global__ __launch_bounds__(256, 2) void symcon_mfma(
    const float* __restrict__ x,  const float* __restrict__ y,
    const float* __restrict__ w1_l0, const float* __restrict__ w2_l0, const float* __restrict__ w3_l0,
    const float* __restrict__ w1_l1, const float* __restrict__ w2_l1, const float* __restrict__ w3_l1,
    const _Float16* __restrict__ Tp, float* __restrict__ out)
{
    const int bid = blockIdx.x;
    const int bb  = (bid >> 2) * BG;       // first b of group
    const int cb  = (bid & 3) * 64;        // c-quarter base
    const int tid = threadIdx.x;
    const int w   = __builtin_amdgcn_readfirstlane(tid >> 6);  // wave id, SGPR
    const int ln  = tid & 63;

    __shared__ __align__(16) _Float16 Mh[64 * MPITCH];       // 29696 B (reused as basis f32)
    __shared__ __align__(16) _Float16 wt4[BG][WT_CH][64];    // 25600 B

    // ---- PW: stage w~ for 4 b's (each weight load feeds 4 FMAs) ----
    {
        float yb[BG][E_DIM];
        #pragma unroll
        for (int g = 0; g < BG; ++g)
            #pragma unroll
            for (int e = 0; e < E_DIM; ++e) yb[g][e] = y[(bb + g)*E_DIM + e];

        for (int v = tid; v < WT_CH * 16; v += 256) {
            int kk = v >> 4;                 // 0..49
            int c4 = (v & 15) << 2;          // 0,4,..,60
            int t  = (kk >= 25) ? kk - 25 : kk;
            const float* wp;
            int ke;
            if (t < K3)            { wp = (kk >= 25 ? w3_l0 : w3_l1) + (size_t)t*C_DIM;        ke = K3; }
            else if (t < K3 + K2)  { wp = (kk >= 25 ? w2_l0 : w2_l1) + (size_t)(t - K3)*C_DIM; ke = K2; }
            else                   { wp = (kk >= 25 ? w1_l0 : w1_l1);                          ke = K1; }
            float s[BG][4];
            #pragma unroll
            for (int g = 0; g < BG; ++g)
                #pragma unroll
                for (int j = 0; j < 4; ++j) s[g][j] = 0.f;
            #pragma unroll
            for (int e = 0; e < E_DIM; ++e) {
                float4 wv = *(const float4*)&wp[(size_t)e*ke*C_DIM + cb + c4];
                #pragma unroll
                for (int g = 0; g < BG; ++g) {
                    s[g][0] = fmaf(yb[g][e], wv.x, s[g][0]);
                    s[g][1] = fmaf(yb[g][e], wv.y, s[g][1]);
                    s[g][2] = fmaf(yb[g][e], wv.z, s[g][2]);
                    s[g][3] = fmaf(yb[g][e], wv.w, s[g][3]);
                }
            }
            #pragma unroll
            for (int g = 0; g < BG; ++g) {
                union { _Float16 h[4]; uint2 u2; } cv;
                cv.h[0] = (_Float16)s[g][0]; cv.h[1] = (_Float16)s[g][1];
                cv.h[2] = (_Float16)s[g][2]; cv.h[3] = (_Float16)s[g][3];
                *(uint2*)&wt4[g][kk][c4] = cv.u2;
            }
        }
    }

    // ---- hoist B-fragments into registers (held across the b-loop) ----
    half8 breg[KT_N][2];
    {
        const half8* Bp = (const half8*)Tp;
        #pragma unroll
        for (int kt = 0; kt < KT_N; ++kt) {
            #pragma unroll
            for (int u = 0; u < 2; ++u) {
                int nt = 2*w + u;
                if (nt < NT_N) breg[kt][u] = Bp[(kt*NT_N + nt)*64 + ln];
                else           breg[kt][u] = half8{};
            }
        }
    }
    __syncthreads();

    // ---- loop over the 4 b's ----
    for (int ib = 0; ib < BG; ++ib) {
        const int b = bb + ib;

        // P1: build M from registers
        {
            float xv[ELL];
            #pragma unroll
            for (int i = 0; i < ELL; ++i)
                xv[i] = x[(size_t)(b*C_DIM + cb + ln)*ELL + i];
            _Float16* Mrow = &Mh[ln * MPITCH];
            switch (w) {
                case 0:  build_M_chunk<0>(xv, Mrow); break;
                case 1:  build_M_chunk<1>(xv, Mrow); break;
                case 2:  build_M_chunk<2>(xv, Mrow); break;
                default: build_M_chunk<3>(xv, Mrow); break;
            }
        }
        __syncthreads();

        // P3: GEMM (A from LDS, B from registers)
        f32x4 acc[2][4];
        #pragma unroll
        for (int u = 0; u < 2; ++u)
            #pragma unroll
            for (int rt = 0; rt < 4; ++rt) acc[u][rt] = (f32x4){0.f, 0.f, 0.f, 0.f};
        {
            const int l15 = ln & 15, lq = ln >> 4;
            #pragma unroll
            for (int kt = 0; kt < KT_N; ++kt) {
                half8 ar[4];
                #pragma unroll
                for (int rt = 0; rt < 4; ++rt)
                    ar[rt] = *(const half8*)&Mh[(rt*16 + l15)*MPITCH + kt*32 + lq*8];
                #pragma unroll
                for (int u = 0; u < 2; ++u) {
                    if (2*w + u < NT_N) {
                        #pragma unroll
                        for (int rt = 0; rt < 4; ++rt)
                            acc[u][rt] = __builtin_amdgcn_mfma_f32_16x16x32_f16(ar[rt], breg[kt][u], acc[u][rt], 0, 0, 0);
                    }
                }
            }
        }
        __syncthreads();   // all waves done reading Mh

        // P4: basis -> LDS (D layout: col = ln&15, row = (ln>>4)*4 + j)
        {
            float* basis = (float*)Mh;
            const int l15 = ln & 15, lq = ln >> 4;
            #pragma unroll
            for (int u = 0; u < 2; ++u) {
                int nt = 2*w + u;
                if (nt < NT_N) {
                    #pragma unroll
                    for (int rt = 0; rt < 4; ++rt)
                        #pragma unroll
                        for (int j = 0; j < 4; ++j)
                            basis[(rt*16 + lq*4 + j)*BPITCH + nt*16 + l15] = acc[u][rt][j];
                }
            }
        }
        __syncthreads();

        // P5: epilogue — wave = q, lane = row
        {
            const float* basis = (const float*)Mh;
            const float* brow  = basis + ln*BPITCH + w*28;
            const int    base  = (w == 0) ? 25 : 0;       // l0 rows at 25..49
            float o = 0.f;
            #pragma unroll
            for (int k = 0; k < K3 + K2 + K1; ++k)
                o = fmaf((float)wt4[ib][base + k][ln], brow[k], o);

            const int c = cb + ln;
            if (w == 0) out[b*C_DIM + c] = o;
            else        out[B_DIM*C_DIM + (size_t)(b*C_DIM + c)*3 + (w - 1)] = o;
        }
        __syncthreads();   // protect Mh before next iteration's P1
    }
}

// ---------------------------------------------------------------------------
extern "C" void kernel_launch(void* const* d_in, const int* in_sizes, int n_in,
                              void* d_out, int out_size, void* d_ws, size_t ws_size,
                              hipStream_t stream)
{
    const float* x     = (const float*)d_in[0];
    const float* y     = (const float*)d_in[1];
    const float* U1_l0 = (const float*)d_in[2];
    const float* U2_l0 = (const float*)d_in[3];
    const float* U3_l0 = (const float*)d_in[4];
    const float* U1_l1 = (const float*)d_in[5];
    const float* U2_l1 = (const float*)d_in[6];
    const float* U3_l1 = (const float*)d_in[7];
    const float* w1_l0 = (const float*)d_in[8];
    const float* w2_l0 = (const float*)d_in[9];
    const float* w3_l0 = (const float*)d_in[10];
    const float* w1_l1 = (const float*)d_in[11];
    const float* w2_l1 = (const float*)d_in[12];
    const float* w3_l1 = (const float*)d_in[13];

    _Float16* Tp   = (_Float16*)d_ws;     // 50176 B used
    float*    outp = (float*)d_out;

    build_tables<<<(TP_ELEMS + 255)/256, 256, 0, stream>>>(
        U1_l0, U2_l0, U3_l0, U1_l1, U2_l1, U3_l1, Tp);

    symcon_mfma<<<(B_DIM/BG) * 4, 256, 0, stream>>>(
        x, y, w1_l0, w2_l0, w3_l0, w1_l1, w2_l1, w3_l1, Tp, outp);
}

// Round 11
// 40.354 us; speedup vs baseline: 5.0901x; 1.1104x over previous
//
#include <hip/hip_runtime.h>

#define B_DIM 1024
#define C_DIM 256
#define ELL   9
#define E_DIM 10
#define K1    1
#define K2    4
#define K3    20

// GEMM geometry: M = B*C rows, K = 224 (219 monomials + pad), N = 112 (4q x 28)
#define N_MONO3 165
#define N_MONO2 45
#define N_MONO  219
#define K_PAD   224
#define KT_N    7            // 224 / 32
#define NT_N    7            // 112 / 16
#define TP_ELEMS (KT_N * NT_N * 64 * 8)   // 25088 fp16, fragment-ordered B
#define MPITCH  232          // fp16 pitch of M rows (464B = 29 quads -> b128 conflict-free)
#define BT_P    66           // fp16 pitch of transposed basis bT[112][66]
#define WT_CH   50           // 25 l1 channels + 25 l0 channels
#define XS_P    12           // f32 pitch of xs[64][12] (48B = 3 quads -> b128 ok)

typedef _Float16 half8 __attribute__((ext_vector_type(8)));
typedef float    f32x4 __attribute__((ext_vector_type(4)));

// ---------------------------------------------------------------------------
// Symmetrized coefficient T[k][n] (validated r8-r10).
// ---------------------------------------------------------------------------
__device__ float table_val(int k, int n,
    const float* U1_l0, const float* U2_l0, const float* U3_l0,
    const float* U1_l1, const float* U2_l1, const float* U3_l1)
{
    int q = n / 28, t = n % 28;
    if (t >= 25 || k >= N_MONO) return 0.f;
    if (k < N_MONO3) {
        if (t >= K3) return 0.f;
        int a=0,b=0,c=0,cnt=0;
        for (int ai=0; ai<ELL; ++ai)
            for (int bi=ai; bi<ELL; ++bi)
                for (int ci=bi; ci<ELL; ++ci) { if (cnt==k){a=ai;b=bi;c=ci;} ++cnt; }
        int P[6][3] = {{a,b,c},{a,c,b},{b,a,c},{b,c,a},{c,a,b},{c,b,a}};
        float s = 0.f;
        for (int tt=0; tt<6; ++tt) {
            bool dup=false;
            for (int u=0; u<tt; ++u)
                if (P[u][0]==P[tt][0]&&P[u][1]==P[tt][1]&&P[u][2]==P[tt][2]) {dup=true;break;}
            if (dup) continue;
            int p0=P[tt][0], p1=P[tt][1], p2=P[tt][2];
            s += (q==0) ? U3_l0[((p0*ELL+p1)*ELL+p2)*K3 + t]
                        : U3_l1[((((q-1)*ELL+p0)*ELL+p1)*ELL+p2)*K3 + t];
        }
        return s;
    } else if (k < N_MONO3 + N_MONO2) {
        if (t < K3 || t >= K3 + K2) return 0.f;
        int pidx = k - N_MONO3, kk = t - K3;
        int a=0,b=0,cnt=0;
        for (int ai=0; ai<ELL; ++ai)
            for (int bi=ai; bi<ELL; ++bi) { if (cnt==pidx){a=ai;b=bi;} ++cnt; }
        float s = 0.f;
        for (int tt=0; tt<2; ++tt) {
            if (tt==1 && a==b) break;
            int p0 = tt ? b : a, p1 = tt ? a : b;
            s += (q==0) ? U2_l0[(p0*ELL+p1)*K2 + kk]
                        : U2_l1[(((q-1)*ELL+p0)*ELL+p1)*K2 + kk];
        }
        return s;
    } else {
        if (t != K3 + K2) return 0.f;
        int i = k - (N_MONO3 + N_MONO2);
        return (q==0) ? U1_l0[i] : U1_l1[(q-1)*ELL + i];
    }
}

// ---------------------------------------------------------------------------
// Kernel A: pack T into MFMA B-fragment order (fp16).  (validated r8-r10)
// ---------------------------------------------------------------------------
__global__ void build_tables(const float* __restrict__ U1_l0,
                             const float* __restrict__ U2_l0,
                             const float* __restrict__ U3_l0,
                             const float* __restrict__ U1_l1,
                             const float* __restrict__ U2_l1,
                             const float* __restrict__ U3_l1,
                             _Float16* __restrict__ Tp)
{
    int idx = blockIdx.x * blockDim.x + threadIdx.x;
    if (idx >= TP_ELEMS) return;
    int e    = idx & 7;
    int lane = (idx >> 3) & 63;
    int tile = idx >> 9;            // 0..48
    int nt   = tile % NT_N;
    int kt   = tile / NT_N;
    int k = kt*32 + (lane >> 4)*8 + e;
    int n = nt*16 + (lane & 15);
    Tp[idx] = (_Float16)table_val(k, n, U1_l0, U2_l0, U3_l0, U1_l1, U2_l1, U3_l1);
}

// ---------------------------------------------------------------------------
// Register-resident monomial emitter (validated r9/r10), now packing 8 fp16
// per ds_write_b128 (row stride 29 quads -> conflict-free writes).
// ---------------------------------------------------------------------------
template<int CH>
__device__ __forceinline__ void build_M_chunk(const float* xv, _Float16* Mrow)
{
    constexpr int LO = CH*56, HI = LO + 56;
    union { _Float16 h[8]; uint4 u4; } pk;
    int m = 0;
#define EMIT(val)                                                       \
    do { if (m >= LO && m < HI) {                                       \
            pk.h[m & 7] = (_Float16)(val);                              \
            if ((m & 7) == 7) *(uint4*)&Mrow[m - 7] = pk.u4;            \
         } ++m; } while (0)

    #pragma unroll
    for (int a = 0; a < ELL; ++a)
        #pragma unroll
        for (int b = a; b < ELL; ++b) {
            float xab = xv[a] * xv[b];
            #pragma unroll
            for (int c = b; c < ELL; ++c) EMIT(xab * xv[c]);
        }
    #pragma unroll
    for (int a = 0; a < ELL; ++a)
        #pragma unroll
        for (int b = a; b < ELL; ++b) EMIT(xv[a] * xv[b]);
    #pragma unroll
    for (int i = 0; i < ELL; ++i) EMIT(xv[i]);
    #pragma unroll
    for (int p = 0; p < K_PAD - N_MONO; ++p) EMIT(0.f);
#undef EMIT
}

// ---------------------------------------------------------------------------
// Kernel B: 2048 blocks x 256 thr; block = 128 rows of one b (2 tiles of 64).
// Per tile: S coalesced-stage xs + wt | P1 build M (LDS-read x, b128 writes) |
// P3 GEMM (B in regs, hoisted once per block) | P4 basis->fp16 transposed bT |
// P5 epilogue (all-LDS).
// ---------------------------------------------------------------------------
__global__ __launch_bounds__(256, 4) void symcon_mfma(
    const float* __restrict__ x,  const float* __restrict__ y,
    const float* __restrict__ w1_l0, const float* __restrict__ w2_l0, const float* __restrict__ w3_l0,
    const float* __restrict__ w1_l1, const float* __restrict__ w2_l1, const float* __restrict__ w3_l1,
    const _Float16* __restrict__ Tp, float* __restrict__ out)
{
    const int bb  = blockIdx.x * 128;      // first bc-row of block
    const int b   = bb >> 8;
    const int cb0 = bb & 255;              // 0 or 128
    const int tid = threadIdx.x;
    const int w   = __builtin_amdgcn_readfirstlane(tid >> 6);  // wave id, SGPR
    const int ln  = tid & 63;

    __shared__ __align__(16) _Float16 Mh[64 * MPITCH];   // 29696 B (P4+ reuses as bT[112][66])
    __shared__ __align__(16) float    xs[64 * XS_P];     //  3072 B
    __shared__ __align__(16) _Float16 wt[WT_CH][64];     //  6400 B

    float yb[E_DIM];
    #pragma unroll
    for (int e = 0; e < E_DIM; ++e) yb[e] = y[b*E_DIM + e];   // uniform -> s_load

    // ---- hoist B-fragments (held across both tiles) ----
    half8 breg[KT_N][2];
    {
        const half8* Bp = (const half8*)Tp;
        #pragma unroll
        for (int kt = 0; kt < KT_N; ++kt)
            #pragma unroll
            for (int u = 0; u < 2; ++u) {
                int nt = 2*w + u;
                if (nt < NT_N) breg[kt][u] = Bp[(kt*NT_N + nt)*64 + ln];
            }
    }

    for (int it = 0; it < 2; ++it) {
        const int row0 = bb + it*64;       // first bc-row of tile
        const int cb   = cb0 + it*64;      // c base of tile

        // ---- S: coalesced x staging + w~ staging ----
        for (int t = tid; t < 64*ELL; t += 256) {
            int r = t / ELL, i = t - r*ELL;
            xs[r*XS_P + i] = x[(size_t)row0*ELL + t];
        }
        for (int v = tid; v < WT_CH * 16; v += 256) {
            int kk = v >> 4;                 // 0..49
            int c4 = (v & 15) << 2;          // 0,4,..,60
            int t  = (kk >= 25) ? kk - 25 : kk;
            const float* wp;
            int ke;
            if (t < K3)            { wp = (kk >= 25 ? w3_l0 : w3_l1) + (size_t)t*C_DIM;        ke = K3; }
            else if (t < K3 + K2)  { wp = (kk >= 25 ? w2_l0 : w2_l1) + (size_t)(t - K3)*C_DIM; ke = K2; }
            else                   { wp = (kk >= 25 ? w1_l0 : w1_l1);                          ke = K1; }
            float s0 = 0.f, s1 = 0.f, s2 = 0.f, s3 = 0.f;
            #pragma unroll
            for (int e = 0; e < E_DIM; ++e) {
                float4 wv = *(const float4*)&wp[(size_t)e*ke*C_DIM + cb + c4];
                s0 = fmaf(yb[e], wv.x, s0);
                s1 = fmaf(yb[e], wv.y, s1);
                s2 = fmaf(yb[e], wv.z, s2);
                s3 = fmaf(yb[e], wv.w, s3);
            }
            union { _Float16 h[4]; uint2 u2; } cv;
            cv.h[0] = (_Float16)s0; cv.h[1] = (_Float16)s1;
            cv.h[2] = (_Float16)s2; cv.h[3] = (_Float16)s3;
            *(uint2*)&wt[kk][c4] = cv.u2;
        }
        __syncthreads();

        // ---- P1: build M from registers (x via 3 LDS vector reads) ----
        {
            float xv[ELL];
            {
                const float4* xr = (const float4*)&xs[ln * XS_P];
                float4 a0 = xr[0], a1 = xr[1];
                xv[0]=a0.x; xv[1]=a0.y; xv[2]=a0.z; xv[3]=a0.w;
                xv[4]=a1.x; xv[5]=a1.y; xv[6]=a1.z; xv[7]=a1.w;
                xv[8]=xs[ln * XS_P + 8];
            }
            _Float16* Mrow = &Mh[ln * MPITCH];
            switch (w) {
                case 0:  build_M_chunk<0>(xv, Mrow); break;
                case 1:  build_M_chunk<1>(xv, Mrow); break;
                case 2:  build_M_chunk<2>(xv, Mrow); break;
                default: build_M_chunk<3>(xv, Mrow); break;
            }
        }
        __syncthreads();

        // ---- P3: GEMM (A from LDS, B from registers) ----
        f32x4 acc[2][4];
        #pragma unroll
        for (int u = 0; u < 2; ++u)
            #pragma unroll
            for (int rt = 0; rt < 4; ++rt) acc[u][rt] = (f32x4){0.f, 0.f, 0.f, 0.f};
        {
            const int l15 = ln & 15, lq = ln >> 4;
            #pragma unroll
            for (int kt = 0; kt < KT_N; ++kt) {
                half8 ar[4];
                #pragma unroll
                for (int rt = 0; rt < 4; ++rt)
                    ar[rt] = *(const half8*)&Mh[(rt*16 + l15)*MPITCH + kt*32 + lq*8];
                #pragma unroll
                for (int u = 0; u < 2; ++u) {
                    if (2*w + u < NT_N) {
                        #pragma unroll
                        for (int rt = 0; rt < 4; ++rt)
                            acc[u][rt] = __builtin_amdgcn_mfma_f32_16x16x32_f16(ar[rt], breg[kt][u], acc[u][rt], 0, 0, 0);
                    }
                }
            }
        }
        __syncthreads();   // all waves done reading Mh

        // ---- P4: basis (fp16) -> transposed bT[112][66] in Mh region ----
        {
            _Float16* bT = Mh;
            const int l15 = ln & 15, lq = ln >> 4;
            #pragma unroll
            for (int u = 0; u < 2; ++u) {
                int nt = 2*w + u;
                if (nt < NT_N) {
                    #pragma unroll
                    for (int rt = 0; rt < 4; ++rt)
                        #pragma unroll
                        for (int j2 = 0; j2 < 2; ++j2) {
                            union { _Float16 h[2]; unsigned int uu; } cv;
                            cv.h[0] = (_Float16)acc[u][rt][2*j2];
                            cv.h[1] = (_Float16)acc[u][rt][2*j2 + 1];
                            *(unsigned int*)&bT[(nt*16 + l15)*BT_P + rt*16 + lq*4 + 2*j2] = cv.uu;
                        }
                }
            }
        }
        __syncthreads();

        // ---- P5: epilogue — wave = q, lane = row ----
        {
            const _Float16* bT = Mh;
            const int base = (w == 0) ? 25 : 0;       // l0 wt rows at 25..49
            float o = 0.f;
            #pragma unroll
            for (int k = 0; k < K3 + K2 + K1; ++k) {
                float bv = (float)bT[(w*28 + k)*BT_P + ln];
                float wv = (float)wt[base + k][ln];
                o = fmaf(wv, bv, o);
            }
            const int c = cb + ln;
            if (w == 0) out[b*C_DIM + c] = o;
            else        out[B_DIM*C_DIM + (size_t)(b*C_DIM + c)*3 + (w - 1)] = o;
        }
        __syncthreads();   // protect xs/wt/Mh before next tile
    }
}

// ---------------------------------------------------------------------------
extern "C" void kernel_launch(void* const* d_in, const int* in_sizes, int n_in,
                              void* d_out, int out_size, void* d_ws, size_t ws_size,
                              hipStream_t stream)
{
    const float* x     = (const float*)d_in[0];
    const float* y     = (const float*)d_in[1];
    const float* U1_l0 = (const float*)d_in[2];
    const float* U2_l0 = (const float*)d_in[3];
    const float* U3_l0 = (const float*)d_in[4];
    const float* U1_l1 = (const float*)d_in[5];
    const float* U2_l1 = (const float*)d_in[6];
    const float* U3_l1 = (const float*)d_in[7];
    const float* w1_l0 = (const float*)d_in[8];
    const float* w2_l0 = (const float*)d_in[9];
    const float* w3_l0 = (const float*)d_in[10];
    const float* w1_l1 = (const float*)d_in[11];
    const float* w2_l1 = (const float*)d_in[12];
    const float* w3_l1 = (const float*)d_in[13];

    _Float16* Tp   = (_Float16*)d_ws;     // 50176 B used
    float*    outp = (float*)d_out;

    build_tables<<<(TP_ELEMS + 255)/256, 256, 0, stream>>>(
        U1_l0, U2_l0, U3_l0, U1_l1, U2_l1, U3_l1, Tp);

    symcon_mfma<<<(B_DIM*C_DIM)/128, 256, 0, stream>>>(
        x, y, w1_l0, w2_l0, w3_l0, w1_l1, w2_l1, w3_l1, Tp, outp);
}